// Round 1
// baseline (1501.793 us; speedup 1.0000x reference)
//
#include <hip/hip_runtime.h>
#include <cstdint>
#include <cstddef>

// CoaT factorized attention block, MI355X/gfx950.
// Pipeline: f32->bf16 casts -> qkv MFMA GEMM -> softmax stats -> kv einsum
//           -> depthwise conv (3/5/7 per head group) -> factor_att+CRPE combine
//           -> proj MFMA GEMM.
// Workspace use ~187 MB. Pad rows (M 25120 -> 25216) carry poison but only
// contaminate pad output rows which are never stored (A row m -> C row m only).

typedef unsigned short u16;

#define HEADS 8
#define CHD   64
#define CDIM  512
#define NTOK  785
#define BATCH 32
#define MROWS (BATCH * NTOK)   // 25120
#define MPAD  25216            // 197 * 128
#define QKVN  1536
#define IMGHW 784

typedef float  f32x4  __attribute__((ext_vector_type(4)));
typedef __bf16 bf16x8 __attribute__((ext_vector_type(8)));

__device__ __forceinline__ u16 f2bf(float f) {
  union { float f; uint32_t u; } x; x.f = f;
  uint32_t r = x.u + 0x7fffu + ((x.u >> 16) & 1u);  // RNE
  return (u16)(r >> 16);
}
__device__ __forceinline__ float bf2f(u16 u) {
  union { uint32_t u; float f; } x; x.u = ((uint32_t)u) << 16;
  return x.f;
}

struct alignas(8) U16x4 { u16 x, y, z, w; };

// ---------------- f32 -> bf16 cast (vectorized, n divisible by 4) ----------
__global__ void f2bf_kernel(const float* __restrict__ in, u16* __restrict__ out, int n4) {
  int i = blockIdx.x * blockDim.x + threadIdx.x;
  if (i >= n4) return;
  float4 v = reinterpret_cast<const float4*>(in)[i];
  U16x4 o; o.x = f2bf(v.x); o.y = f2bf(v.y); o.z = f2bf(v.z); o.w = f2bf(v.w);
  reinterpret_cast<U16x4*>(out)[i] = o;
}

// ---------------- async global->LDS, 16B per lane --------------------------
__device__ __forceinline__ void gld_lds16(const u16* g, u16* l) {
  __builtin_amdgcn_global_load_lds((__attribute__((address_space(1))) void*)g,
                                   (__attribute__((address_space(3))) void*)l,
                                   16, 0, 0);
}

// ---------------- bf16 MFMA GEMM, C = A @ W^T + bias -----------------------
// A: (Mtiles*128, K) bf16 row-major. W: (N, K) bf16 row-major. K % 32 == 0.
// 128x128 tile, 4 waves in 2x2, each wave 4x4 of 16x16x32 MFMA.
template <int OUTBF16>
__global__ __launch_bounds__(256)
void gemm_bt(const u16* __restrict__ A, const u16* __restrict__ W,
             const float* __restrict__ bias, void* __restrict__ Cout,
             int Mstore, int N, int K) {
  __shared__ __align__(16) u16 lsA[128 * 32];
  __shared__ __align__(16) u16 lsB[128 * 32];
  const int tid  = threadIdx.x;
  const int wave = tid >> 6, lane = tid & 63;
  const int quad = lane >> 4, l16 = lane & 15;
  const int tile_m = blockIdx.x * 128;
  const int tile_n = blockIdx.y * 128;
  const int wm = (wave & 1) * 64, wn = (wave >> 1) * 64;

  f32x4 acc[4][4] = {};

  const int srow = tid >> 2;          // 0..63
  const int scol = (tid & 3) * 8;     // 0,8,16,24

  for (int k0 = 0; k0 < K; k0 += 32) {
#pragma unroll
    for (int r = 0; r < 2; ++r) {
      const u16* ga = A + (size_t)(tile_m + r * 64 + srow) * K + k0 + scol;
      gld_lds16(ga, &lsA[(r * 256 + wave * 64) * 8]);
      const u16* gb = W + (size_t)(tile_n + r * 64 + srow) * K + k0 + scol;
      gld_lds16(gb, &lsB[(r * 256 + wave * 64) * 8]);
    }
    __syncthreads();
    bf16x8 af[4], bfr[4];
#pragma unroll
    for (int i = 0; i < 4; ++i) {
      af[i]  = *reinterpret_cast<const bf16x8*>(&lsA[(wm + i * 16 + l16) * 32 + quad * 8]);
      bfr[i] = *reinterpret_cast<const bf16x8*>(&lsB[(wn + i * 16 + l16) * 32 + quad * 8]);
    }
#pragma unroll
    for (int i = 0; i < 4; ++i)
#pragma unroll
      for (int j = 0; j < 4; ++j)
        acc[i][j] = __builtin_amdgcn_mfma_f32_16x16x32_bf16(af[i], bfr[j], acc[i][j], 0, 0, 0);
    __syncthreads();
  }

  // C/D layout: col = lane&15, row = quad*4 + reg  [verified m89/m91]
#pragma unroll
  for (int i = 0; i < 4; ++i) {
    const int mbase = tile_m + wm + i * 16 + quad * 4;
#pragma unroll
    for (int j = 0; j < 4; ++j) {
      const int n  = tile_n + wn + j * 16 + l16;
      const float bv = bias[n];
#pragma unroll
      for (int r = 0; r < 4; ++r) {
        const int mm = mbase + r;
        if (mm < Mstore) {
          const float v = acc[i][j][r] + bv;
          if (OUTBF16) reinterpret_cast<u16*>(Cout)[(size_t)mm * N + n] = f2bf(v);
          else         reinterpret_cast<float*>(Cout)[(size_t)mm * N + n] = v;
        }
      }
    }
  }
}

// ---------------- softmax stats over n per (b,h,c) -------------------------
// qkv layout: (B*785, 1536) bf16, col = part*512 + h*64 + c (part: 0=q,1=k,2=v)
__global__ __launch_bounds__(256)
void softmax_stats_kernel(const u16* __restrict__ qkv,
                          float* __restrict__ maxv, float* __restrict__ rsum) {
  const int bh = blockIdx.x;              // b*8 + h
  const int b = bh >> 3, h = bh & 7;
  const int t = threadIdx.x;
  const int c = t & 63, part = t >> 6;    // 4-way split over n
  float m = -1e30f, s = 0.f;
  const u16* base = qkv + (size_t)(b * NTOK) * QKVN + CDIM + h * CHD + c;
  for (int n = part; n < NTOK; n += 4) {
    float v = bf2f(base[(size_t)n * QKVN]);
    if (v > m) { s = s * __expf(m - v) + 1.f; m = v; }
    else       { s += __expf(v - m); }
  }
  __shared__ float sm[256], ss[256];
  sm[t] = m; ss[t] = s;
  __syncthreads();
  if (part == 0) {
    float M = m, S = s;
#pragma unroll
    for (int p = 1; p < 4; ++p) {
      float mp = sm[p * 64 + c], sp = ss[p * 64 + c];
      float Mn = fmaxf(M, mp);
      S = S * __expf(M - Mn) + sp * __expf(mp - Mn);
      M = Mn;
    }
    maxv[bh * 64 + c] = M;
    rsum[bh * 64 + c] = 1.f / S;
  }
}

// ---------------- kv[b,h,c,d] = sum_n softmax(k)[n,c] * v[n,d] -------------
__global__ __launch_bounds__(256)
void kv_kernel(const u16* __restrict__ qkv, const float* __restrict__ maxv,
               const float* __restrict__ rsum, float* __restrict__ kvout) {
  const int bh = blockIdx.x;
  const int b = bh >> 3, h = bh & 7;
  const int t = threadIdx.x;
  const int d = t & 63, cq = t >> 6;
  __shared__ float e_s[32 * 64];
  __shared__ float v_s[32 * 64];
  __shared__ float mx[64];
  if (t < 64) mx[t] = maxv[bh * 64 + t];
  const u16* kbase = qkv + (size_t)(b * NTOK) * QKVN + CDIM + h * CHD;
  const u16* vbase = kbase + CDIM;   // v part
  float acc[16];
#pragma unroll
  for (int i = 0; i < 16; ++i) acc[i] = 0.f;

  for (int n0 = 0; n0 < NTOK; n0 += 32) {
    const int nc = min(32, NTOK - n0);
    __syncthreads();   // covers mx init and previous-iteration reads
    for (int i = t; i < nc * 64; i += 256) {
      const int nl = i >> 6, c = i & 63;
      e_s[i] = __expf(bf2f(kbase[(size_t)(n0 + nl) * QKVN + c]) - mx[c]);
      v_s[i] = bf2f(vbase[(size_t)(n0 + nl) * QKVN + c]);
    }
    __syncthreads();
    for (int nl = 0; nl < nc; ++nl) {
      const float vv = v_s[nl * 64 + d];
#pragma unroll
      for (int i = 0; i < 16; ++i)
        acc[i] += e_s[nl * 64 + cq * 16 + i] * vv;   // broadcast read: cq wave-uniform
    }
  }
#pragma unroll
  for (int i = 0; i < 16; ++i) {
    const int c = cq * 16 + i;
    kvout[((size_t)bh * 64 + c) * 64 + d] = acc[i] * rsum[bh * 64 + c];
  }
}

// ---------------- depthwise conv on v image --------------------------------
// cg = h*64 + d in [0,512): cg<128 -> 3x3 (w3), cg<320 -> 5x5 (w5), else 7x7 (w7).
// Boundaries are wave-aligned (128, 320 multiples of 64) -> no divergence.
// Output convv layout: ((b*8+h)*784 + p)*64 + d   (coalesced for combine kernel).
__global__ __launch_bounds__(512)
void conv_kernel(const u16* __restrict__ qkv,
                 const float* __restrict__ w3, const float* __restrict__ b3,
                 const float* __restrict__ w5, const float* __restrict__ b5,
                 const float* __restrict__ w7, const float* __restrict__ b7,
                 float* __restrict__ convv) {
  const int bp = blockIdx.x;            // b*784 + p
  const int b = bp / IMGHW, p = bp - b * IMGHW;
  const int y = p / 28, x = p - y * 28;
  const int cg = threadIdx.x;           // 0..511
  int ks; const float* w; float bias;
  if (cg < 128)      { ks = 3; w = w3 + cg * 9;          bias = b3[cg]; }
  else if (cg < 320) { ks = 5; w = w5 + (cg - 128) * 25; bias = b5[cg - 128]; }
  else               { ks = 7; w = w7 + (cg - 320) * 49; bias = b7[cg - 320]; }
  const int pad = ks >> 1;
  const u16* vbase = qkv + (size_t)(b * NTOK + 1) * QKVN + 2 * CDIM + cg;
  float acc = bias;
  for (int dy = 0; dy < ks; ++dy) {
    const int yy = y + dy - pad;
    if (yy < 0 || yy >= 28) continue;
    for (int dx = 0; dx < ks; ++dx) {
      const int xx = x + dx - pad;
      if (xx < 0 || xx >= 28) continue;
      acc += w[dy * ks + dx] * bf2f(vbase[(size_t)(yy * 28 + xx) * QKVN]);
    }
  }
  const int h = cg >> 6, d = cg & 63;
  convv[(((size_t)b * 8 + h) * IMGHW + p) * 64 + d] = acc;
}

// ---------------- factor_att + CRPE -> attn (bf16, (B*785, 512)) -----------
__global__ __launch_bounds__(256)
void combine_kernel(const u16* __restrict__ qkv, const float* __restrict__ kvbuf,
                    const float* __restrict__ convv, u16* __restrict__ attn) {
  const int bh = blockIdx.x;
  const int b = bh >> 3, h = bh & 7;
  const int t = threadIdx.x;
  const int d = t & 63, nq = t >> 6;
  __shared__ float kv_s[64 * 64];
  __shared__ float q_s[2][4][64];
  for (int i = t; i < 4096; i += 256) kv_s[i] = kvbuf[(size_t)bh * 4096 + i];
  const u16* qbase = qkv + (size_t)(b * NTOK) * QKVN + h * CHD;
  const float* cbase = convv + (size_t)bh * IMGHW * 64;
  const float scale = 0.125f;  // Ch^-0.5 = 1/8
  int buf = 0;
  for (int n0 = 0; n0 < NTOK; n0 += 4) {
    const int nn = n0 + nq;
    if (nn < NTOK) q_s[buf][nq][d] = bf2f(qbase[(size_t)nn * QKVN + d]);
    __syncthreads();   // also covers initial kv_s staging
    if (nn < NTOK) {
      float dot = 0.f;
#pragma unroll 8
      for (int c = 0; c < 64; ++c) dot += q_s[buf][nq][c] * kv_s[c * 64 + d];
      float out = scale * dot;
      if (nn > 0) out += q_s[buf][nq][d] * cbase[(size_t)(nn - 1) * 64 + d];
      attn[((size_t)(b * NTOK + nn)) * CDIM + h * CHD + d] = f2bf(out);
    }
    buf ^= 1;  // double buffer: one barrier per iter is sufficient
  }
}

// ---------------- launch ---------------------------------------------------
extern "C" void kernel_launch(void* const* d_in, const int* in_sizes, int n_in,
                              void* d_out, int out_size, void* d_ws, size_t ws_size,
                              hipStream_t stream) {
  const float* x      = (const float*)d_in[0];
  const float* qkv_w  = (const float*)d_in[1];
  const float* qkv_b  = (const float*)d_in[2];
  const float* proj_w = (const float*)d_in[3];
  const float* proj_b = (const float*)d_in[4];
  const float* w3 = (const float*)d_in[5];
  const float* b3 = (const float*)d_in[6];
  const float* w5 = (const float*)d_in[7];
  const float* b5 = (const float*)d_in[8];
  const float* w7 = (const float*)d_in[9];
  const float* b7 = (const float*)d_in[10];
  float* out = (float*)d_out;

  // workspace carve-up (all offsets 16B-aligned)
  char* p = (char*)d_ws;
  u16* xb    = (u16*)p;   p += (size_t)MPAD * CDIM * 2;      // 25.8 MB
  u16* wqb   = (u16*)p;   p += (size_t)QKVN * CDIM * 2;      // 1.5 MB
  u16* wpb   = (u16*)p;   p += (size_t)CDIM * CDIM * 2;      // 0.5 MB
  u16* qkvb  = (u16*)p;   p += (size_t)MPAD * QKVN * 2;      // 77.5 MB
  float* maxv = (float*)p; p += 256 * 64 * 4;
  float* rsum = (float*)p; p += 256 * 64 * 4;
  float* kvbuf = (float*)p; p += (size_t)256 * 64 * 64 * 4;  // 4 MB
  float* convv = (float*)p; p += (size_t)256 * IMGHW * 64 * 4; // 51.4 MB
  u16* attn  = (u16*)p;   p += (size_t)MPAD * CDIM * 2;      // 25.8 MB

  // 1. casts to bf16
  {
    int n4 = (MROWS * CDIM) / 4;
    f2bf_kernel<<<(n4 + 255) / 256, 256, 0, stream>>>(x, xb, n4);
    n4 = (QKVN * CDIM) / 4;
    f2bf_kernel<<<(n4 + 255) / 256, 256, 0, stream>>>(qkv_w, wqb, n4);
    n4 = (CDIM * CDIM) / 4;
    f2bf_kernel<<<(n4 + 255) / 256, 256, 0, stream>>>(proj_w, wpb, n4);
  }
  // 2. qkv = x @ qkv_w^T + qkv_b  (bf16 out)
  gemm_bt<1><<<dim3(MPAD / 128, QKVN / 128), 256, 0, stream>>>(
      xb, wqb, qkv_b, qkvb, MPAD, QKVN, CDIM);
  // 3. softmax stats over n per (b,h,c)
  softmax_stats_kernel<<<256, 256, 0, stream>>>(qkvb, maxv, rsum);
  // 4. kv einsum
  kv_kernel<<<256, 256, 0, stream>>>(qkvb, maxv, rsum, kvbuf);
  // 5. depthwise convs on v image
  conv_kernel<<<BATCH * IMGHW, 512, 0, stream>>>(qkvb, w3, b3, w5, b5, w7, b7, convv);
  // 6. factor_att + CRPE -> attn (bf16)
  combine_kernel<<<256, 256, 0, stream>>>(qkvb, kvbuf, convv, attn);
  // 7. out = attn @ proj_w^T + proj_b  (f32 out, guarded at 25120 rows)
  gemm_bt<0><<<dim3(MPAD / 128, CDIM / 128), 256, 0, stream>>>(
      attn, wpb, proj_b, out, MROWS, CDIM, CDIM);
}

// Round 2
// 698.639 us; speedup vs baseline: 2.1496x; 2.1496x over previous
//
#include <hip/hip_runtime.h>
#include <cstdint>
#include <cstddef>

// CoaT factorized attention block, MI355X/gfx950.
// R2: conv rewritten — LDS-tiled, compile-time kernel size, column-streaming
// register accumulation (was: runtime-ks scalar-load latency disaster, 873us).

typedef unsigned short u16;

#define HEADS 8
#define CHD   64
#define CDIM  512
#define NTOK  785
#define BATCH 32
#define MROWS (BATCH * NTOK)   // 25120
#define MPAD  25216            // 197 * 128
#define QKVN  1536
#define IMGHW 784

typedef float  f32x4  __attribute__((ext_vector_type(4)));
typedef __bf16 bf16x8 __attribute__((ext_vector_type(8)));

__device__ __forceinline__ u16 f2bf(float f) {
  union { float f; uint32_t u; } x; x.f = f;
  uint32_t r = x.u + 0x7fffu + ((x.u >> 16) & 1u);  // RNE
  return (u16)(r >> 16);
}
__device__ __forceinline__ float bf2f(u16 u) {
  union { uint32_t u; float f; } x; x.u = ((uint32_t)u) << 16;
  return x.f;
}

struct alignas(8) U16x4 { u16 x, y, z, w; };

// ---------------- f32 -> bf16 cast (vectorized, n divisible by 4) ----------
__global__ void f2bf_kernel(const float* __restrict__ in, u16* __restrict__ out, int n4) {
  int i = blockIdx.x * blockDim.x + threadIdx.x;
  if (i >= n4) return;
  float4 v = reinterpret_cast<const float4*>(in)[i];
  U16x4 o; o.x = f2bf(v.x); o.y = f2bf(v.y); o.z = f2bf(v.z); o.w = f2bf(v.w);
  reinterpret_cast<U16x4*>(out)[i] = o;
}

// ---------------- async global->LDS, 16B per lane --------------------------
__device__ __forceinline__ void gld_lds16(const u16* g, u16* l) {
  __builtin_amdgcn_global_load_lds((__attribute__((address_space(1))) void*)g,
                                   (__attribute__((address_space(3))) void*)l,
                                   16, 0, 0);
}

// ---------------- bf16 MFMA GEMM, C = A @ W^T + bias -----------------------
// A: (Mtiles*128, K) bf16 row-major. W: (N, K) bf16 row-major. K % 32 == 0.
// 128x128 tile, 4 waves in 2x2, each wave 4x4 of 16x16x32 MFMA.
template <int OUTBF16>
__global__ __launch_bounds__(256)
void gemm_bt(const u16* __restrict__ A, const u16* __restrict__ W,
             const float* __restrict__ bias, void* __restrict__ Cout,
             int Mstore, int N, int K) {
  __shared__ __align__(16) u16 lsA[128 * 32];
  __shared__ __align__(16) u16 lsB[128 * 32];
  const int tid  = threadIdx.x;
  const int wave = tid >> 6, lane = tid & 63;
  const int quad = lane >> 4, l16 = lane & 15;
  const int tile_m = blockIdx.x * 128;
  const int tile_n = blockIdx.y * 128;
  const int wm = (wave & 1) * 64, wn = (wave >> 1) * 64;

  f32x4 acc[4][4] = {};

  const int srow = tid >> 2;          // 0..63
  const int scol = (tid & 3) * 8;     // 0,8,16,24

  for (int k0 = 0; k0 < K; k0 += 32) {
#pragma unroll
    for (int r = 0; r < 2; ++r) {
      const u16* ga = A + (size_t)(tile_m + r * 64 + srow) * K + k0 + scol;
      gld_lds16(ga, &lsA[(r * 256 + wave * 64) * 8]);
      const u16* gb = W + (size_t)(tile_n + r * 64 + srow) * K + k0 + scol;
      gld_lds16(gb, &lsB[(r * 256 + wave * 64) * 8]);
    }
    __syncthreads();
    bf16x8 af[4], bfr[4];
#pragma unroll
    for (int i = 0; i < 4; ++i) {
      af[i]  = *reinterpret_cast<const bf16x8*>(&lsA[(wm + i * 16 + l16) * 32 + quad * 8]);
      bfr[i] = *reinterpret_cast<const bf16x8*>(&lsB[(wn + i * 16 + l16) * 32 + quad * 8]);
    }
#pragma unroll
    for (int i = 0; i < 4; ++i)
#pragma unroll
      for (int j = 0; j < 4; ++j)
        acc[i][j] = __builtin_amdgcn_mfma_f32_16x16x32_bf16(af[i], bfr[j], acc[i][j], 0, 0, 0);
    __syncthreads();
  }

  // C/D layout: col = lane&15, row = quad*4 + reg  [verified m89/m91]
#pragma unroll
  for (int i = 0; i < 4; ++i) {
    const int mbase = tile_m + wm + i * 16 + quad * 4;
#pragma unroll
    for (int j = 0; j < 4; ++j) {
      const int n  = tile_n + wn + j * 16 + l16;
      const float bv = bias[n];
#pragma unroll
      for (int r = 0; r < 4; ++r) {
        const int mm = mbase + r;
        if (mm < Mstore) {
          const float v = acc[i][j][r] + bv;
          if (OUTBF16) reinterpret_cast<u16*>(Cout)[(size_t)mm * N + n] = f2bf(v);
          else         reinterpret_cast<float*>(Cout)[(size_t)mm * N + n] = v;
        }
      }
    }
  }
}

// ---------------- softmax stats over n per (b,h,c) -------------------------
__global__ __launch_bounds__(256)
void softmax_stats_kernel(const u16* __restrict__ qkv,
                          float* __restrict__ maxv, float* __restrict__ rsum) {
  const int bh = blockIdx.x;              // b*8 + h
  const int b = bh >> 3, h = bh & 7;
  const int t = threadIdx.x;
  const int c = t & 63, part = t >> 6;    // 4-way split over n
  float m = -1e30f, s = 0.f;
  const u16* base = qkv + (size_t)(b * NTOK) * QKVN + CDIM + h * CHD + c;
  for (int n = part; n < NTOK; n += 4) {
    float v = bf2f(base[(size_t)n * QKVN]);
    if (v > m) { s = s * __expf(m - v) + 1.f; m = v; }
    else       { s += __expf(v - m); }
  }
  __shared__ float sm[256], ss[256];
  sm[t] = m; ss[t] = s;
  __syncthreads();
  if (part == 0) {
    float M = m, S = s;
#pragma unroll
    for (int p = 1; p < 4; ++p) {
      float mp = sm[p * 64 + c], sp = ss[p * 64 + c];
      float Mn = fmaxf(M, mp);
      S = S * __expf(M - Mn) + sp * __expf(mp - Mn);
      M = Mn;
    }
    maxv[bh * 64 + c] = M;
    rsum[bh * 64 + c] = 1.f / S;
  }
}

// ---------------- kv[b,h,c,d] = sum_n softmax(k)[n,c] * v[n,d] -------------
__global__ __launch_bounds__(256)
void kv_kernel(const u16* __restrict__ qkv, const float* __restrict__ maxv,
               const float* __restrict__ rsum, float* __restrict__ kvout) {
  const int bh = blockIdx.x;
  const int b = bh >> 3, h = bh & 7;
  const int t = threadIdx.x;
  const int d = t & 63, cq = t >> 6;
  __shared__ float e_s[32 * 64];
  __shared__ float v_s[32 * 64];
  __shared__ float mx[64];
  if (t < 64) mx[t] = maxv[bh * 64 + t];
  const u16* kbase = qkv + (size_t)(b * NTOK) * QKVN + CDIM + h * CHD;
  const u16* vbase = kbase + CDIM;   // v part
  float acc[16];
#pragma unroll
  for (int i = 0; i < 16; ++i) acc[i] = 0.f;

  for (int n0 = 0; n0 < NTOK; n0 += 32) {
    const int nc = min(32, NTOK - n0);
    __syncthreads();   // covers mx init and previous-iteration reads
    for (int i = t; i < nc * 64; i += 256) {
      const int nl = i >> 6, c = i & 63;
      e_s[i] = __expf(bf2f(kbase[(size_t)(n0 + nl) * QKVN + c]) - mx[c]);
      v_s[i] = bf2f(vbase[(size_t)(n0 + nl) * QKVN + c]);
    }
    __syncthreads();
    for (int nl = 0; nl < nc; ++nl) {
      const float vv = v_s[nl * 64 + d];
#pragma unroll
      for (int i = 0; i < 16; ++i)
        acc[i] += e_s[nl * 64 + cq * 16 + i] * vv;
    }
  }
#pragma unroll
  for (int i = 0; i < 16; ++i) {
    const int c = cq * 16 + i;
    kvout[((size_t)bh * 64 + c) * 64 + d] = acc[i] * rsum[bh * 64 + c];
  }
}

// ---------------- depthwise conv: LDS-tiled, compile-time KS ---------------
// Block = (b, head, ytile of 4 rows). One head -> one KS (groups 64-aligned).
// Stage RIN=4+2*PAD input rows x 28 x 64ch (bf16) into LDS with 16B loads;
// column-streaming compute: per input col, KS LDS reads + KS^2 FMAs into 28
// per-thread accumulators (x-padding = compile-time tap bounds, y-padding =
// zero-filled LDS halo). Wave = one row-group x 64 ch: conflict-free LDS
// (2B stride = free 2-way), coalesced 256B stores.
template <int KS>
__device__ __forceinline__ void conv_head(
    const u16* __restrict__ qkv, const float* __restrict__ wgt,
    const float* __restrict__ bias, int b, int head, int hh, int yt,
    float* __restrict__ convv, u16* __restrict__ ls) {
  constexpr int PAD = KS / 2;
  constexpr int RIN = 4 + 2 * PAD;
  const int t = threadIdx.x;
  const int y0 = yt * 4;
  const u16* vimg = qkv + (size_t)(b * NTOK + 1) * QKVN + 2 * CDIM + head * 64;
  // stage RIN*28 pixels, 64 ch each = 128B/pixel = 8 lanes * 16B
  const int c8 = (t & 7) * 8;
  for (int pi = t >> 3; pi < RIN * 28; pi += 32) {
    const int ry = pi / 28, rx = pi - ry * 28;
    const int yy = y0 - PAD + ry;
    uint4 val = {0, 0, 0, 0};
    if (yy >= 0 && yy < 28)
      val = *reinterpret_cast<const uint4*>(vimg + (size_t)(yy * 28 + rx) * QKVN + c8);
    *reinterpret_cast<uint4*>(ls + pi * 64 + c8) = val;
  }
  __syncthreads();
  const int d = t & 63, yl = t >> 6;       // wave-uniform yl
  float wr[KS * KS];
  const float* wp = wgt + (hh * 64 + d) * KS * KS;
#pragma unroll
  for (int i = 0; i < KS * KS; ++i) wr[i] = wp[i];
  const float bv = bias[hh * 64 + d];
  float acc[28];
#pragma unroll
  for (int x = 0; x < 28; ++x) acc[x] = bv;
#pragma unroll
  for (int xx = 0; xx < 28; ++xx) {
    float col[KS];
#pragma unroll
    for (int r = 0; r < KS; ++r)
      col[r] = bf2f(ls[((yl + r) * 28 + xx) * 64 + d]);
#pragma unroll
    for (int j = 0; j < KS; ++j) {
      const int x = xx + PAD - j;
      if (x >= 0 && x < 28) {
#pragma unroll
        for (int r = 0; r < KS; ++r)
          acc[x] += col[r] * wr[r * KS + j];
      }
    }
  }
  float* obase = convv + (((size_t)(b * 8 + head)) * IMGHW + (size_t)(y0 + yl) * 28) * 64 + d;
#pragma unroll
  for (int x = 0; x < 28; ++x) obase[(size_t)x * 64] = acc[x];
}

__global__ __launch_bounds__(256)
void conv_all_kernel(const u16* __restrict__ qkv,
                     const float* __restrict__ w3, const float* __restrict__ b3,
                     const float* __restrict__ w5, const float* __restrict__ b5,
                     const float* __restrict__ w7, const float* __restrict__ b7,
                     float* __restrict__ convv) {
  __shared__ __align__(16) u16 ls[10 * 28 * 64];   // worst case KS=7: 35840 B
  const int b = blockIdx.x, h = blockIdx.y, yt = blockIdx.z;
  if (h < 2)      conv_head<3>(qkv, w3, b3, b, h, h,     yt, convv, ls);
  else if (h < 5) conv_head<5>(qkv, w5, b5, b, h, h - 2, yt, convv, ls);
  else            conv_head<7>(qkv, w7, b7, b, h, h - 5, yt, convv, ls);
}

// ---------------- factor_att + CRPE -> attn (bf16, (B*785, 512)) -----------
__global__ __launch_bounds__(256)
void combine_kernel(const u16* __restrict__ qkv, const float* __restrict__ kvbuf,
                    const float* __restrict__ convv, u16* __restrict__ attn) {
  const int bh = blockIdx.x;
  const int b = bh >> 3, h = bh & 7;
  const int t = threadIdx.x;
  const int d = t & 63, nq = t >> 6;
  __shared__ float kv_s[64 * 64];
  __shared__ float q_s[2][4][64];
  for (int i = t; i < 4096; i += 256) kv_s[i] = kvbuf[(size_t)bh * 4096 + i];
  const u16* qbase = qkv + (size_t)(b * NTOK) * QKVN + h * CHD;
  const float* cbase = convv + (size_t)bh * IMGHW * 64;
  const float scale = 0.125f;  // Ch^-0.5 = 1/8
  int buf = 0;
  for (int n0 = 0; n0 < NTOK; n0 += 4) {
    const int nn = n0 + nq;
    if (nn < NTOK) q_s[buf][nq][d] = bf2f(qbase[(size_t)nn * QKVN + d]);
    __syncthreads();   // also covers initial kv_s staging
    if (nn < NTOK) {
      float dot = 0.f;
#pragma unroll 8
      for (int c = 0; c < 64; ++c) dot += q_s[buf][nq][c] * kv_s[c * 64 + d];
      float out = scale * dot;
      if (nn > 0) out += q_s[buf][nq][d] * cbase[(size_t)(nn - 1) * 64 + d];
      attn[((size_t)(b * NTOK + nn)) * CDIM + h * CHD + d] = f2bf(out);
    }
    buf ^= 1;
  }
}

// ---------------- launch ---------------------------------------------------
extern "C" void kernel_launch(void* const* d_in, const int* in_sizes, int n_in,
                              void* d_out, int out_size, void* d_ws, size_t ws_size,
                              hipStream_t stream) {
  const float* x      = (const float*)d_in[0];
  const float* qkv_w  = (const float*)d_in[1];
  const float* qkv_b  = (const float*)d_in[2];
  const float* proj_w = (const float*)d_in[3];
  const float* proj_b = (const float*)d_in[4];
  const float* w3 = (const float*)d_in[5];
  const float* b3 = (const float*)d_in[6];
  const float* w5 = (const float*)d_in[7];
  const float* b5 = (const float*)d_in[8];
  const float* w7 = (const float*)d_in[9];
  const float* b7 = (const float*)d_in[10];
  float* out = (float*)d_out;

  char* p = (char*)d_ws;
  u16* xb    = (u16*)p;   p += (size_t)MPAD * CDIM * 2;
  u16* wqb   = (u16*)p;   p += (size_t)QKVN * CDIM * 2;
  u16* wpb   = (u16*)p;   p += (size_t)CDIM * CDIM * 2;
  u16* qkvb  = (u16*)p;   p += (size_t)MPAD * QKVN * 2;
  float* maxv = (float*)p; p += 256 * 64 * 4;
  float* rsum = (float*)p; p += 256 * 64 * 4;
  float* kvbuf = (float*)p; p += (size_t)256 * 64 * 64 * 4;
  float* convv = (float*)p; p += (size_t)256 * IMGHW * 64 * 4;
  u16* attn  = (u16*)p;   p += (size_t)MPAD * CDIM * 2;

  {
    int n4 = (MROWS * CDIM) / 4;
    f2bf_kernel<<<(n4 + 255) / 256, 256, 0, stream>>>(x, xb, n4);
    n4 = (QKVN * CDIM) / 4;
    f2bf_kernel<<<(n4 + 255) / 256, 256, 0, stream>>>(qkv_w, wqb, n4);
    n4 = (CDIM * CDIM) / 4;
    f2bf_kernel<<<(n4 + 255) / 256, 256, 0, stream>>>(proj_w, wpb, n4);
  }
  gemm_bt<1><<<dim3(MPAD / 128, QKVN / 128), 256, 0, stream>>>(
      xb, wqb, qkv_b, qkvb, MPAD, QKVN, CDIM);
  softmax_stats_kernel<<<256, 256, 0, stream>>>(qkvb, maxv, rsum);
  kv_kernel<<<256, 256, 0, stream>>>(qkvb, maxv, rsum, kvbuf);
  conv_all_kernel<<<dim3(BATCH, HEADS, 7), 256, 0, stream>>>(
      qkvb, w3, b3, w5, b5, w7, b7, convv);
  combine_kernel<<<256, 256, 0, stream>>>(qkvb, kvbuf, convv, attn);
  gemm_bt<0><<<dim3(MPAD / 128, CDIM / 128), 256, 0, stream>>>(
      attn, wpb, proj_b, out, MROWS, CDIM, CDIM);
}

// Round 3
// 426.836 us; speedup vs baseline: 3.5184x; 1.6368x over previous
//
#include <hip/hip_runtime.h>
#include <cstdint>
#include <cstddef>

// CoaT factorized attention block, MI355X/gfx950.
// R3: combine rewritten as per-head MFMA GEMM (was 258us serial-loop latency
// disaster); EV (q*conv) fused into conv epilogue (bf16); kv einsum split 7x
// over tokens with f32 partials + tiny reduce/transpose to bf16 kvT.

typedef unsigned short u16;

#define HEADS 8
#define CHD   64
#define CDIM  512
#define NTOK  785
#define BATCH 32
#define MROWS (BATCH * NTOK)   // 25120
#define MPAD  25216            // 197 * 128
#define QKVN  1536
#define IMGHW 784
#define KVSPLIT 7

typedef float  f32x4  __attribute__((ext_vector_type(4)));
typedef __bf16 bf16x8 __attribute__((ext_vector_type(8)));

__device__ __forceinline__ u16 f2bf(float f) {
  union { float f; uint32_t u; } x; x.f = f;
  uint32_t r = x.u + 0x7fffu + ((x.u >> 16) & 1u);  // RNE
  return (u16)(r >> 16);
}
__device__ __forceinline__ float bf2f(u16 u) {
  union { uint32_t u; float f; } x; x.u = ((uint32_t)u) << 16;
  return x.f;
}

struct alignas(8) U16x4 { u16 x, y, z, w; };

// ---------------- f32 -> bf16 cast (vectorized, n divisible by 4) ----------
__global__ void f2bf_kernel(const float* __restrict__ in, u16* __restrict__ out, int n4) {
  int i = blockIdx.x * blockDim.x + threadIdx.x;
  if (i >= n4) return;
  float4 v = reinterpret_cast<const float4*>(in)[i];
  U16x4 o; o.x = f2bf(v.x); o.y = f2bf(v.y); o.z = f2bf(v.z); o.w = f2bf(v.w);
  reinterpret_cast<U16x4*>(out)[i] = o;
}

// ---------------- async global->LDS, 16B per lane --------------------------
__device__ __forceinline__ void gld_lds16(const u16* g, u16* l) {
  __builtin_amdgcn_global_load_lds((__attribute__((address_space(1))) void*)g,
                                   (__attribute__((address_space(3))) void*)l,
                                   16, 0, 0);
}

// ---------------- bf16 MFMA GEMM, C = A @ W^T + bias -----------------------
template <int OUTBF16>
__global__ __launch_bounds__(256)
void gemm_bt(const u16* __restrict__ A, const u16* __restrict__ W,
             const float* __restrict__ bias, void* __restrict__ Cout,
             int Mstore, int N, int K) {
  __shared__ __align__(16) u16 lsA[128 * 32];
  __shared__ __align__(16) u16 lsB[128 * 32];
  const int tid  = threadIdx.x;
  const int wave = tid >> 6, lane = tid & 63;
  const int quad = lane >> 4, l16 = lane & 15;
  const int tile_m = blockIdx.x * 128;
  const int tile_n = blockIdx.y * 128;
  const int wm = (wave & 1) * 64, wn = (wave >> 1) * 64;

  f32x4 acc[4][4] = {};

  const int srow = tid >> 2;          // 0..63
  const int scol = (tid & 3) * 8;     // 0,8,16,24

  for (int k0 = 0; k0 < K; k0 += 32) {
#pragma unroll
    for (int r = 0; r < 2; ++r) {
      const u16* ga = A + (size_t)(tile_m + r * 64 + srow) * K + k0 + scol;
      gld_lds16(ga, &lsA[(r * 256 + wave * 64) * 8]);
      const u16* gb = W + (size_t)(tile_n + r * 64 + srow) * K + k0 + scol;
      gld_lds16(gb, &lsB[(r * 256 + wave * 64) * 8]);
    }
    __syncthreads();
    bf16x8 af[4], bfr[4];
#pragma unroll
    for (int i = 0; i < 4; ++i) {
      af[i]  = *reinterpret_cast<const bf16x8*>(&lsA[(wm + i * 16 + l16) * 32 + quad * 8]);
      bfr[i] = *reinterpret_cast<const bf16x8*>(&lsB[(wn + i * 16 + l16) * 32 + quad * 8]);
    }
#pragma unroll
    for (int i = 0; i < 4; ++i)
#pragma unroll
      for (int j = 0; j < 4; ++j)
        acc[i][j] = __builtin_amdgcn_mfma_f32_16x16x32_bf16(af[i], bfr[j], acc[i][j], 0, 0, 0);
    __syncthreads();
  }

  // C/D layout: col = lane&15, row = quad*4 + reg
#pragma unroll
  for (int i = 0; i < 4; ++i) {
    const int mbase = tile_m + wm + i * 16 + quad * 4;
#pragma unroll
    for (int j = 0; j < 4; ++j) {
      const int n  = tile_n + wn + j * 16 + l16;
      const float bv = bias[n];
#pragma unroll
      for (int r = 0; r < 4; ++r) {
        const int mm = mbase + r;
        if (mm < Mstore) {
          const float v = acc[i][j][r] + bv;
          if (OUTBF16) reinterpret_cast<u16*>(Cout)[(size_t)mm * N + n] = f2bf(v);
          else         reinterpret_cast<float*>(Cout)[(size_t)mm * N + n] = v;
        }
      }
    }
  }
}

// ---------------- softmax stats over n per (b,h,c) -------------------------
__global__ __launch_bounds__(256)
void softmax_stats_kernel(const u16* __restrict__ qkv,
                          float* __restrict__ maxv, float* __restrict__ rsum) {
  const int bh = blockIdx.x;              // b*8 + h
  const int b = bh >> 3, h = bh & 7;
  const int t = threadIdx.x;
  const int c = t & 63, part = t >> 6;    // 4-way split over n
  float m = -1e30f, s = 0.f;
  const u16* base = qkv + (size_t)(b * NTOK) * QKVN + CDIM + h * CHD + c;
  for (int n = part; n < NTOK; n += 4) {
    float v = bf2f(base[(size_t)n * QKVN]);
    if (v > m) { s = s * __expf(m - v) + 1.f; m = v; }
    else       { s += __expf(v - m); }
  }
  __shared__ float sm[256], ss[256];
  sm[t] = m; ss[t] = s;
  __syncthreads();
  if (part == 0) {
    float M = m, S = s;
#pragma unroll
    for (int p = 1; p < 4; ++p) {
      float mp = sm[p * 64 + c], sp = ss[p * 64 + c];
      float Mn = fmaxf(M, mp);
      S = S * __expf(M - Mn) + sp * __expf(mp - Mn);
      M = Mn;
    }
    maxv[bh * 64 + c] = M;
    rsum[bh * 64 + c] = 1.f / S;
  }
}

// ---------------- kv partials: kvpart[bh][split][c][d] ---------------------
// Each block handles ~113 tokens of one (b,h); no rsum yet.
__global__ __launch_bounds__(256)
void kv_kernel(const u16* __restrict__ qkv, const float* __restrict__ maxv,
               float* __restrict__ kvpart) {
  const int bh = blockIdx.x, split = blockIdx.y;
  const int b = bh >> 3, h = bh & 7;
  const int n_start = split * 113;
  const int n_end = min(NTOK, n_start + 113);
  const int t = threadIdx.x;
  const int d = t & 63, cq = t >> 6;
  __shared__ float e_s[32 * 64];
  __shared__ float v_s[32 * 64];
  __shared__ float mx[64];
  if (t < 64) mx[t] = maxv[bh * 64 + t];
  const u16* kbase = qkv + (size_t)(b * NTOK) * QKVN + CDIM + h * CHD;
  const u16* vbase = kbase + CDIM;
  float acc[16];
#pragma unroll
  for (int i = 0; i < 16; ++i) acc[i] = 0.f;

  for (int n0 = n_start; n0 < n_end; n0 += 32) {
    const int nc = min(32, n_end - n0);
    __syncthreads();
    for (int i = t; i < nc * 64; i += 256) {
      const int nl = i >> 6, c = i & 63;
      e_s[i] = __expf(bf2f(kbase[(size_t)(n0 + nl) * QKVN + c]) - mx[c]);
      v_s[i] = bf2f(vbase[(size_t)(n0 + nl) * QKVN + c]);
    }
    __syncthreads();
    for (int nl = 0; nl < nc; ++nl) {
      const float vv = v_s[nl * 64 + d];
#pragma unroll
      for (int i = 0; i < 16; ++i)
        acc[i] += e_s[nl * 64 + cq * 16 + i] * vv;
    }
  }
#pragma unroll
  for (int i = 0; i < 16; ++i) {
    const int c = cq * 16 + i;
    kvpart[(((size_t)bh * KVSPLIT + split) * 64 + c) * 64 + d] = acc[i];
  }
}

// ---------------- reduce partials -> kvT[bh][d][c] bf16 (B-operand layout) -
__global__ __launch_bounds__(256)
void kv_reduce_kernel(const float* __restrict__ kvpart, const float* __restrict__ rsum,
                      u16* __restrict__ kvT) {
  const int bh = blockIdx.x;
  const int t = threadIdx.x;
  const int d = t & 63, cq = t >> 6;
#pragma unroll
  for (int cc = 0; cc < 16; ++cc) {
    const int c = cq * 16 + cc;
    float s = 0.f;
#pragma unroll
    for (int sp = 0; sp < KVSPLIT; ++sp)
      s += kvpart[(((size_t)bh * KVSPLIT + sp) * 64 + c) * 64 + d];
    kvT[(size_t)bh * 4096 + d * 64 + c] = f2bf(s * rsum[bh * 64 + c]);
  }
}

// ---------------- depthwise conv + EV fuse ---------------------------------
// Block = (b, head, ytile of 4 rows). EV[p][d] = conv[p][d] * q[token p+1][d],
// stored bf16 at evbuf[(bh*784+p)*64+d].
template <int KS>
__device__ __forceinline__ void conv_head(
    const u16* __restrict__ qkv, const float* __restrict__ wgt,
    const float* __restrict__ bias, int b, int head, int hh, int yt,
    u16* __restrict__ evbuf, u16* __restrict__ ls) {
  constexpr int PAD = KS / 2;
  constexpr int RIN = 4 + 2 * PAD;
  const int t = threadIdx.x;
  const int y0 = yt * 4;
  const u16* vimg = qkv + (size_t)(b * NTOK + 1) * QKVN + 2 * CDIM + head * 64;
  const int c8 = (t & 7) * 8;
  for (int pi = t >> 3; pi < RIN * 28; pi += 32) {
    const int ry = pi / 28, rx = pi - ry * 28;
    const int yy = y0 - PAD + ry;
    uint4 val = {0, 0, 0, 0};
    if (yy >= 0 && yy < 28)
      val = *reinterpret_cast<const uint4*>(vimg + (size_t)(yy * 28 + rx) * QKVN + c8);
    *reinterpret_cast<uint4*>(ls + pi * 64 + c8) = val;
  }
  __syncthreads();
  const int d = t & 63, yl = t >> 6;       // wave-uniform yl
  float wr[KS * KS];
  const float* wp = wgt + (hh * 64 + d) * KS * KS;
#pragma unroll
  for (int i = 0; i < KS * KS; ++i) wr[i] = wp[i];
  const float bv = bias[hh * 64 + d];
  float acc[28];
#pragma unroll
  for (int x = 0; x < 28; ++x) acc[x] = bv;
#pragma unroll
  for (int xx = 0; xx < 28; ++xx) {
    float col[KS];
#pragma unroll
    for (int r = 0; r < KS; ++r)
      col[r] = bf2f(ls[((yl + r) * 28 + xx) * 64 + d]);
#pragma unroll
    for (int j = 0; j < KS; ++j) {
      const int x = xx + PAD - j;
      if (x >= 0 && x < 28) {
#pragma unroll
        for (int r = 0; r < KS; ++r)
          acc[x] += col[r] * wr[r * KS + j];
      }
    }
  }
  const int p0 = (y0 + yl) * 28;           // pixel row base
  const u16* qrow = qkv + (size_t)(b * NTOK + 1 + p0) * QKVN + head * 64 + d;
  u16* obase = evbuf + (((size_t)(b * 8 + head)) * IMGHW + p0) * 64 + d;
#pragma unroll
  for (int x = 0; x < 28; ++x) {
    const float ev = acc[x] * bf2f(qrow[(size_t)x * QKVN]);
    obase[(size_t)x * 64] = f2bf(ev);
  }
}

__global__ __launch_bounds__(256)
void conv_all_kernel(const u16* __restrict__ qkv,
                     const float* __restrict__ w3, const float* __restrict__ b3,
                     const float* __restrict__ w5, const float* __restrict__ b5,
                     const float* __restrict__ w7, const float* __restrict__ b7,
                     u16* __restrict__ evbuf) {
  __shared__ __align__(16) u16 ls[10 * 28 * 64];   // worst case KS=7: 35840 B
  const int b = blockIdx.x, h = blockIdx.y, yt = blockIdx.z;
  if (h < 2)      conv_head<3>(qkv, w3, b3, b, h, h,     yt, evbuf, ls);
  else if (h < 5) conv_head<5>(qkv, w5, b5, b, h, h - 2, yt, evbuf, ls);
  else            conv_head<7>(qkv, w7, b7, b, h, h - 5, yt, evbuf, ls);
}

// ---------------- combine: factor_att via MFMA + CRPE ----------------------
// Grid (bh, 4 token-tiles of 256). Wave handles 64 tokens x 64 d:
// A-frags direct from q (global, K-contiguous), B-frags from kvT (global).
__global__ __launch_bounds__(256)
void combine_kernel(const u16* __restrict__ qkv, const u16* __restrict__ kvT,
                    const u16* __restrict__ evbuf, u16* __restrict__ attn) {
  const int bh = blockIdx.x;
  const int b = bh >> 3, h = bh & 7;
  const int wave = threadIdx.x >> 6, lane = threadIdx.x & 63;
  const int quad = lane >> 4, l16 = lane & 15;
  const int tokbase = blockIdx.y * 256 + wave * 64;

  const u16* kvb = kvT + (size_t)bh * 4096;
  bf16x8 bfr[4][2];
#pragma unroll
  for (int j = 0; j < 4; ++j)
#pragma unroll
    for (int kk = 0; kk < 2; ++kk)
      bfr[j][kk] = *reinterpret_cast<const bf16x8*>(
          &kvb[(j * 16 + l16) * 64 + kk * 32 + quad * 8]);

  bf16x8 af[4][2];
#pragma unroll
  for (int i = 0; i < 4; ++i) {
    const int tok = min(tokbase + i * 16 + l16, NTOK - 1);
    const u16* qrow = qkv + (size_t)(b * NTOK + tok) * QKVN + h * CHD;
    af[i][0] = *reinterpret_cast<const bf16x8*>(&qrow[quad * 8]);
    af[i][1] = *reinterpret_cast<const bf16x8*>(&qrow[32 + quad * 8]);
  }

  f32x4 acc[4][4] = {};
#pragma unroll
  for (int kk = 0; kk < 2; ++kk)
#pragma unroll
    for (int i = 0; i < 4; ++i)
#pragma unroll
      for (int j = 0; j < 4; ++j)
        acc[i][j] = __builtin_amdgcn_mfma_f32_16x16x32_bf16(af[i][kk], bfr[j][kk], acc[i][j], 0, 0, 0);

  const float scale = 0.125f;  // Ch^-0.5
  const u16* evb = evbuf + (size_t)bh * IMGHW * 64;
#pragma unroll
  for (int i = 0; i < 4; ++i) {
#pragma unroll
    for (int r = 0; r < 4; ++r) {
      const int tok = tokbase + i * 16 + quad * 4 + r;
      if (tok < NTOK) {
#pragma unroll
        for (int j = 0; j < 4; ++j) {
          const int d = j * 16 + l16;
          float out = scale * acc[i][j][r];
          if (tok > 0) out += bf2f(evb[(size_t)(tok - 1) * 64 + d]);
          attn[(size_t)(b * NTOK + tok) * CDIM + h * CHD + d] = f2bf(out);
        }
      }
    }
  }
}

// ---------------- launch ---------------------------------------------------
extern "C" void kernel_launch(void* const* d_in, const int* in_sizes, int n_in,
                              void* d_out, int out_size, void* d_ws, size_t ws_size,
                              hipStream_t stream) {
  const float* x      = (const float*)d_in[0];
  const float* qkv_w  = (const float*)d_in[1];
  const float* qkv_b  = (const float*)d_in[2];
  const float* proj_w = (const float*)d_in[3];
  const float* proj_b = (const float*)d_in[4];
  const float* w3 = (const float*)d_in[5];
  const float* b3 = (const float*)d_in[6];
  const float* w5 = (const float*)d_in[7];
  const float* b5 = (const float*)d_in[8];
  const float* w7 = (const float*)d_in[9];
  const float* b7 = (const float*)d_in[10];
  float* out = (float*)d_out;

  char* p = (char*)d_ws;
  u16* xb    = (u16*)p;   p += (size_t)MPAD * CDIM * 2;
  u16* wqb   = (u16*)p;   p += (size_t)QKVN * CDIM * 2;
  u16* wpb   = (u16*)p;   p += (size_t)CDIM * CDIM * 2;
  u16* qkvb  = (u16*)p;   p += (size_t)MPAD * QKVN * 2;
  float* maxv = (float*)p; p += 256 * 64 * 4;
  float* rsum = (float*)p; p += 256 * 64 * 4;
  u16* kvT   = (u16*)p;   p += (size_t)256 * 64 * 64 * 2;           // 2 MB
  // kvpart (f32, 29 MB) and evbuf (bf16, 25.7 MB) share one region:
  // kvpart is dead after kv_reduce; conv writes evbuf afterwards.
  char* shared_region = p;
  float* kvpart = (float*)shared_region;   // 256*7*64*64*4 = 29.4 MB
  u16*   evbuf  = (u16*)shared_region;     // 256*784*64*2  = 25.7 MB
  p += (size_t)256 * KVSPLIT * 64 * 64 * 4;
  u16* attn  = (u16*)p;   p += (size_t)MPAD * CDIM * 2;

  {
    int n4 = (MROWS * CDIM) / 4;
    f2bf_kernel<<<(n4 + 255) / 256, 256, 0, stream>>>(x, xb, n4);
    n4 = (QKVN * CDIM) / 4;
    f2bf_kernel<<<(n4 + 255) / 256, 256, 0, stream>>>(qkv_w, wqb, n4);
    n4 = (CDIM * CDIM) / 4;
    f2bf_kernel<<<(n4 + 255) / 256, 256, 0, stream>>>(proj_w, wpb, n4);
  }
  gemm_bt<1><<<dim3(MPAD / 128, QKVN / 128), 256, 0, stream>>>(
      xb, wqb, qkv_b, qkvb, MPAD, QKVN, CDIM);
  softmax_stats_kernel<<<256, 256, 0, stream>>>(qkvb, maxv, rsum);
  kv_kernel<<<dim3(256, KVSPLIT), 256, 0, stream>>>(qkvb, maxv, kvpart);
  kv_reduce_kernel<<<256, 256, 0, stream>>>(kvpart, rsum, kvT);
  conv_all_kernel<<<dim3(BATCH, HEADS, 7), 256, 0, stream>>>(
      qkvb, w3, b3, w5, b5, w7, b7, evbuf);
  combine_kernel<<<dim3(256, 4), 256, 0, stream>>>(qkvb, kvT, evbuf, attn);
  gemm_bt<0><<<dim3(MPAD / 128, CDIM / 128), 256, 0, stream>>>(
      attn, wpb, proj_b, out, MROWS, CDIM, CDIM);
}

// Round 4
// 331.195 us; speedup vs baseline: 4.5345x; 1.2888x over previous
//
#include <hip/hip_runtime.h>
#include <cstdint>
#include <cstddef>

// CoaT factorized attention block, MI355X/gfx950.
// R4: GEMM — BK=64 + XOR-8 LDS swizzle (kills 8-way bank conflicts, halves
// barriers), XCD-banded N-fastest grid (kills 6x A re-fetch), packed bf16
// epilogue. softmax_stats kernel deleted (exp-sum fused into kv_kernel; no
// max subtraction needed: |k| small, f32 exp safe). Casts merged to 1 launch.

typedef unsigned short u16;

#define HEADS 8
#define CHD   64
#define CDIM  512
#define NTOK  785
#define BATCH 32
#define MROWS (BATCH * NTOK)   // 25120
#define MPAD  25216            // 197 * 128
#define QKVN  1536
#define IMGHW 784
#define KVSPLIT 7

typedef float  f32x4  __attribute__((ext_vector_type(4)));
typedef __bf16 bf16x8 __attribute__((ext_vector_type(8)));

__device__ __forceinline__ u16 f2bf(float f) {
  union { float f; uint32_t u; } x; x.f = f;
  uint32_t r = x.u + 0x7fffu + ((x.u >> 16) & 1u);  // RNE
  return (u16)(r >> 16);
}
__device__ __forceinline__ float bf2f(u16 u) {
  union { uint32_t u; float f; } x; x.u = ((uint32_t)u) << 16;
  return x.f;
}
// packed f32x2 -> bf16x2 (low = a, high = b)
__device__ __forceinline__ uint32_t pk2(float a, float b) {
#if __has_builtin(__builtin_amdgcn_cvt_pk_bf16_f32)
  auto v = __builtin_amdgcn_cvt_pk_bf16_f32(a, b);
  union { decltype(v) v2; uint32_t u; } cv; cv.v2 = v; return cv.u;
#else
  return (uint32_t)f2bf(a) | ((uint32_t)f2bf(b) << 16);
#endif
}

// ---------------- merged f32 -> bf16 casts (x, qkv_w, proj_w) --------------
__global__ __launch_bounds__(256)
void casts_kernel(const float* __restrict__ x, u16* __restrict__ xb,
                  const float* __restrict__ w1, u16* __restrict__ w1b,
                  const float* __restrict__ w2, u16* __restrict__ w2b) {
  const int N1 = MROWS * CDIM / 4, N2 = QKVN * CDIM / 4, N3 = CDIM * CDIM / 4;
  int i = blockIdx.x * 256 + threadIdx.x;
  const float* src; u16* dst;
  if (i < N1)           { src = x;  dst = xb;  }
  else if (i < N1 + N2) { i -= N1;  src = w1; dst = w1b; }
  else if (i < N1 + N2 + N3) { i -= N1 + N2; src = w2; dst = w2b; }
  else return;
  float4 v = reinterpret_cast<const float4*>(src)[i];
  uint2 o; o.x = pk2(v.x, v.y); o.y = pk2(v.z, v.w);
  reinterpret_cast<uint2*>(dst)[i] = o;
}

// ---------------- async global->LDS, 16B per lane --------------------------
__device__ __forceinline__ void gld_lds16(const u16* g, u16* l) {
  __builtin_amdgcn_global_load_lds((__attribute__((address_space(1))) void*)g,
                                   (__attribute__((address_space(3))) void*)l,
                                   16, 0, 0);
}

// ---------------- bf16 MFMA GEMM, C = A @ W^T + bias -----------------------
// BK=64, XOR-8 chunk swizzle: logical (row, chunk c) stored at physical
// chunk c ^ (row&7) — permutation applied on the GLOBAL side so the
// global_load_lds dest stays wave-uniform-base + lane*16B. Fragment reads
// then hit 8 distinct bank-groups (2 lanes each = free 2-way).
// Grid: flat 1D, XCD-banded, N-fastest: xcd = flat&7; each XCD iterates all
// N-tiles for its M-tile band -> A tile fetched once per XCD L2.
template <int OUTBF16>
__global__ __launch_bounds__(256)
void gemm_bt(const u16* __restrict__ A, const u16* __restrict__ W,
             const float* __restrict__ bias, void* __restrict__ Cout,
             int Mstore, int N, int K, int nMt, int nNt) {
  __shared__ __align__(16) u16 lsA[128 * 64];
  __shared__ __align__(16) u16 lsB[128 * 64];
  const int flat = blockIdx.x;
  const int xcd = flat & 7, idx = flat >> 3;
  const int nt = idx % nNt;
  const int mt = (idx / nNt) * 8 + xcd;
  if (mt >= nMt) return;
  const int tile_m = mt * 128, tile_n = nt * 128;

  const int tid  = threadIdx.x;
  const int wave = tid >> 6, lane = tid & 63;
  const int quad = lane >> 4, l16 = lane & 15;
  const int wm = (wave & 1) * 64, wn = (wave >> 1) * 64;

  // staging: sweep s covers rows s*32 + (tid>>3); lane loads global chunk
  // ((tid&7) ^ ((tid>>3)&7)) -> lands at physical chunk (tid&7).
  const int srow0 = tid >> 3;                       // 0..31
  const int scol  = ((tid & 7) ^ ((tid >> 3) & 7)) * 8;
  const int lbase = wave * 512;                     // + s*2048 (elems)

  f32x4 acc[4][4] = {};

  for (int k0 = 0; k0 < K; k0 += 64) {
#pragma unroll
    for (int s = 0; s < 4; ++s) {
      const int r = s * 32 + srow0;
      gld_lds16(A + (size_t)(tile_m + r) * K + k0 + scol, &lsA[s * 2048 + lbase]);
      gld_lds16(W + (size_t)(tile_n + r) * K + k0 + scol, &lsB[s * 2048 + lbase]);
    }
    __syncthreads();
#pragma unroll
    for (int kk = 0; kk < 2; ++kk) {
      const int pch = ((kk * 4 + quad) ^ (l16 & 7)) * 8;  // physical chunk (elems)
      bf16x8 af[4], bfr[4];
#pragma unroll
      for (int i = 0; i < 4; ++i) {
        af[i]  = *reinterpret_cast<const bf16x8*>(&lsA[(wm + i * 16 + l16) * 64 + pch]);
        bfr[i] = *reinterpret_cast<const bf16x8*>(&lsB[(wn + i * 16 + l16) * 64 + pch]);
      }
#pragma unroll
      for (int i = 0; i < 4; ++i)
#pragma unroll
        for (int j = 0; j < 4; ++j)
          acc[i][j] = __builtin_amdgcn_mfma_f32_16x16x32_bf16(af[i], bfr[j], acc[i][j], 0, 0, 0);
    }
    __syncthreads();
  }

  // C/D layout: col = lane&15, row = quad*4 + reg
#pragma unroll
  for (int i = 0; i < 4; ++i) {
    const int mbase = tile_m + wm + i * 16 + quad * 4;
#pragma unroll
    for (int j = 0; j < 4; ++j) {
      const int n  = tile_n + wn + j * 16 + l16;
      const float bv = bias[n];
      const float v0 = acc[i][j][0] + bv, v1 = acc[i][j][1] + bv;
      const float v2 = acc[i][j][2] + bv, v3 = acc[i][j][3] + bv;
      if (OUTBF16) {
        u16* cp = reinterpret_cast<u16*>(Cout) + (size_t)mbase * N + n;
        const uint32_t p01 = pk2(v0, v1), p23 = pk2(v2, v3);
        if (mbase + 0 < Mstore) cp[0]            = (u16)p01;
        if (mbase + 1 < Mstore) cp[(size_t)N]    = (u16)(p01 >> 16);
        if (mbase + 2 < Mstore) cp[(size_t)N*2]  = (u16)p23;
        if (mbase + 3 < Mstore) cp[(size_t)N*3]  = (u16)(p23 >> 16);
      } else {
        float* cp = reinterpret_cast<float*>(Cout) + (size_t)mbase * N + n;
        if (mbase + 0 < Mstore) cp[0]           = v0;
        if (mbase + 1 < Mstore) cp[(size_t)N]   = v1;
        if (mbase + 2 < Mstore) cp[(size_t)N*2] = v2;
        if (mbase + 3 < Mstore) cp[(size_t)N*3] = v3;
      }
    }
  }
}

// ---------------- kv partials + exp-sum partials ---------------------------
// kvpart[bh][split][c][d] = sum_{n in split} exp(k[n,c]) * v[n,d]
// kvsum [bh][split][c]    = sum_{n in split} exp(k[n,c])
// No max subtraction: k ~ N(0,1), |k| < ~6 -> exp safe in f32.
__global__ __launch_bounds__(256)
void kv_kernel(const u16* __restrict__ qkv, float* __restrict__ kvpart,
               float* __restrict__ kvsum) {
  const int bh = blockIdx.x, split = blockIdx.y;
  const int b = bh >> 3, h = bh & 7;
  const int n_start = split * 113;
  const int n_end = min(NTOK, n_start + 113);
  const int t = threadIdx.x;
  const int d = t & 63, cq = t >> 6;
  __shared__ float e_s[32 * 64];
  __shared__ float v_s[32 * 64];
  const u16* kbase = qkv + (size_t)(b * NTOK) * QKVN + CDIM + h * CHD;
  const u16* vbase = kbase + CDIM;
  float acc[16];
#pragma unroll
  for (int i = 0; i < 16; ++i) acc[i] = 0.f;
  float s_part = 0.f;   // sum of exp over this thread's staged elems (c = t&63)

  for (int n0 = n_start; n0 < n_end; n0 += 32) {
    const int nc = min(32, n_end - n0);
    __syncthreads();
    for (int i = t; i < nc * 64; i += 256) {
      const int nl = i >> 6, c = i & 63;
      const float e = __expf(bf2f(kbase[(size_t)(n0 + nl) * QKVN + c]));
      e_s[i] = e; s_part += e;
      v_s[i] = bf2f(vbase[(size_t)(n0 + nl) * QKVN + c]);
    }
    __syncthreads();
    for (int nl = 0; nl < nc; ++nl) {
      const float vv = v_s[nl * 64 + d];
#pragma unroll
      for (int i = 0; i < 16; ++i)
        acc[i] += e_s[nl * 64 + cq * 16 + i] * vv;
    }
  }
#pragma unroll
  for (int i = 0; i < 16; ++i) {
    const int c = cq * 16 + i;
    kvpart[(((size_t)bh * KVSPLIT + split) * 64 + c) * 64 + d] = acc[i];
  }
  // reduce 4 thread-partials per c
  __syncthreads();
  e_s[t] = s_part;
  __syncthreads();
  if (t < 64)
    kvsum[((size_t)bh * KVSPLIT + split) * 64 + t] =
        e_s[t] + e_s[64 + t] + e_s[128 + t] + e_s[192 + t];
}

// ---------------- reduce partials -> kvT[bh][d][c] bf16 (B-operand layout) -
__global__ __launch_bounds__(256)
void kv_reduce_kernel(const float* __restrict__ kvpart, const float* __restrict__ kvsum,
                      u16* __restrict__ kvT) {
  const int bh = blockIdx.x;
  const int t = threadIdx.x;
  const int d = t & 63, cq = t >> 6;
#pragma unroll
  for (int cc = 0; cc < 16; ++cc) {
    const int c = cq * 16 + cc;
    float s = 0.f, S = 0.f;
#pragma unroll
    for (int sp = 0; sp < KVSPLIT; ++sp) {
      s += kvpart[(((size_t)bh * KVSPLIT + sp) * 64 + c) * 64 + d];
      S += kvsum[((size_t)bh * KVSPLIT + sp) * 64 + c];
    }
    kvT[(size_t)bh * 4096 + d * 64 + c] = f2bf(s / S);
  }
}

// ---------------- depthwise conv + EV fuse ---------------------------------
template <int KS>
__device__ __forceinline__ void conv_head(
    const u16* __restrict__ qkv, const float* __restrict__ wgt,
    const float* __restrict__ bias, int b, int head, int hh, int yt,
    u16* __restrict__ evbuf, u16* __restrict__ ls) {
  constexpr int PAD = KS / 2;
  constexpr int RIN = 4 + 2 * PAD;
  const int t = threadIdx.x;
  const int y0 = yt * 4;
  const u16* vimg = qkv + (size_t)(b * NTOK + 1) * QKVN + 2 * CDIM + head * 64;
  const int c8 = (t & 7) * 8;
  for (int pi = t >> 3; pi < RIN * 28; pi += 32) {
    const int ry = pi / 28, rx = pi - ry * 28;
    const int yy = y0 - PAD + ry;
    uint4 val = {0, 0, 0, 0};
    if (yy >= 0 && yy < 28)
      val = *reinterpret_cast<const uint4*>(vimg + (size_t)(yy * 28 + rx) * QKVN + c8);
    *reinterpret_cast<uint4*>(ls + pi * 64 + c8) = val;
  }
  __syncthreads();
  const int d = t & 63, yl = t >> 6;
  float wr[KS * KS];
  const float* wp = wgt + (hh * 64 + d) * KS * KS;
#pragma unroll
  for (int i = 0; i < KS * KS; ++i) wr[i] = wp[i];
  const float bv = bias[hh * 64 + d];
  float acc[28];
#pragma unroll
  for (int x = 0; x < 28; ++x) acc[x] = bv;
#pragma unroll
  for (int xx = 0; xx < 28; ++xx) {
    float col[KS];
#pragma unroll
    for (int r = 0; r < KS; ++r)
      col[r] = bf2f(ls[((yl + r) * 28 + xx) * 64 + d]);
#pragma unroll
    for (int j = 0; j < KS; ++j) {
      const int x = xx + PAD - j;
      if (x >= 0 && x < 28) {
#pragma unroll
        for (int r = 0; r < KS; ++r)
          acc[x] += col[r] * wr[r * KS + j];
      }
    }
  }
  const int p0 = (y0 + yl) * 28;
  const u16* qrow = qkv + (size_t)(b * NTOK + 1 + p0) * QKVN + head * 64 + d;
  u16* obase = evbuf + (((size_t)(b * 8 + head)) * IMGHW + p0) * 64 + d;
#pragma unroll
  for (int x = 0; x < 28; ++x) {
    const float ev = acc[x] * bf2f(qrow[(size_t)x * QKVN]);
    obase[(size_t)x * 64] = f2bf(ev);
  }
}

__global__ __launch_bounds__(256)
void conv_all_kernel(const u16* __restrict__ qkv,
                     const float* __restrict__ w3, const float* __restrict__ b3,
                     const float* __restrict__ w5, const float* __restrict__ b5,
                     const float* __restrict__ w7, const float* __restrict__ b7,
                     u16* __restrict__ evbuf) {
  __shared__ __align__(16) u16 ls[10 * 28 * 64];
  const int b = blockIdx.x, h = blockIdx.y, yt = blockIdx.z;
  if (h < 2)      conv_head<3>(qkv, w3, b3, b, h, h,     yt, evbuf, ls);
  else if (h < 5) conv_head<5>(qkv, w5, b5, b, h, h - 2, yt, evbuf, ls);
  else            conv_head<7>(qkv, w7, b7, b, h, h - 5, yt, evbuf, ls);
}

// ---------------- combine: factor_att via MFMA + CRPE ----------------------
__global__ __launch_bounds__(256)
void combine_kernel(const u16* __restrict__ qkv, const u16* __restrict__ kvT,
                    const u16* __restrict__ evbuf, u16* __restrict__ attn) {
  const int bh = blockIdx.x;
  const int b = bh >> 3, h = bh & 7;
  const int wave = threadIdx.x >> 6, lane = threadIdx.x & 63;
  const int quad = lane >> 4, l16 = lane & 15;
  const int tokbase = blockIdx.y * 256 + wave * 64;

  const u16* kvb = kvT + (size_t)bh * 4096;
  bf16x8 bfr[4][2];
#pragma unroll
  for (int j = 0; j < 4; ++j)
#pragma unroll
    for (int kk = 0; kk < 2; ++kk)
      bfr[j][kk] = *reinterpret_cast<const bf16x8*>(
          &kvb[(j * 16 + l16) * 64 + kk * 32 + quad * 8]);

  bf16x8 af[4][2];
#pragma unroll
  for (int i = 0; i < 4; ++i) {
    const int tok = min(tokbase + i * 16 + l16, NTOK - 1);
    const u16* qrow = qkv + (size_t)(b * NTOK + tok) * QKVN + h * CHD;
    af[i][0] = *reinterpret_cast<const bf16x8*>(&qrow[quad * 8]);
    af[i][1] = *reinterpret_cast<const bf16x8*>(&qrow[32 + quad * 8]);
  }

  f32x4 acc[4][4] = {};
#pragma unroll
  for (int kk = 0; kk < 2; ++kk)
#pragma unroll
    for (int i = 0; i < 4; ++i)
#pragma unroll
      for (int j = 0; j < 4; ++j)
        acc[i][j] = __builtin_amdgcn_mfma_f32_16x16x32_bf16(af[i][kk], bfr[j][kk], acc[i][j], 0, 0, 0);

  const float scale = 0.125f;
  const u16* evb = evbuf + (size_t)bh * IMGHW * 64;
#pragma unroll
  for (int i = 0; i < 4; ++i) {
#pragma unroll
    for (int r = 0; r < 4; ++r) {
      const int tok = tokbase + i * 16 + quad * 4 + r;
      if (tok < NTOK) {
#pragma unroll
        for (int j = 0; j < 4; ++j) {
          const int d = j * 16 + l16;
          float out = scale * acc[i][j][r];
          if (tok > 0) out += bf2f(evb[(size_t)(tok - 1) * 64 + d]);
          attn[(size_t)(b * NTOK + tok) * CDIM + h * CHD + d] = f2bf(out);
        }
      }
    }
  }
}

// ---------------- launch ---------------------------------------------------
extern "C" void kernel_launch(void* const* d_in, const int* in_sizes, int n_in,
                              void* d_out, int out_size, void* d_ws, size_t ws_size,
                              hipStream_t stream) {
  const float* x      = (const float*)d_in[0];
  const float* qkv_w  = (const float*)d_in[1];
  const float* qkv_b  = (const float*)d_in[2];
  const float* proj_w = (const float*)d_in[3];
  const float* proj_b = (const float*)d_in[4];
  const float* w3 = (const float*)d_in[5];
  const float* b3 = (const float*)d_in[6];
  const float* w5 = (const float*)d_in[7];
  const float* b5 = (const float*)d_in[8];
  const float* w7 = (const float*)d_in[9];
  const float* b7 = (const float*)d_in[10];
  float* out = (float*)d_out;

  char* p = (char*)d_ws;
  u16* xb    = (u16*)p;   p += (size_t)MPAD * CDIM * 2;
  u16* wqb   = (u16*)p;   p += (size_t)QKVN * CDIM * 2;
  u16* wpb   = (u16*)p;   p += (size_t)CDIM * CDIM * 2;
  u16* qkvb  = (u16*)p;   p += (size_t)MPAD * QKVN * 2;
  float* kvsum = (float*)p; p += (size_t)256 * KVSPLIT * 64 * 4;
  u16* kvT   = (u16*)p;   p += (size_t)256 * 64 * 64 * 2;
  // kvpart (f32, 29.4 MB) and evbuf (bf16, 25.7 MB) share one region:
  // kvpart dead after kv_reduce; conv writes evbuf afterwards.
  char* shared_region = p;
  float* kvpart = (float*)shared_region;
  u16*   evbuf  = (u16*)shared_region;
  p += (size_t)256 * KVSPLIT * 64 * 64 * 4;
  u16* attn  = (u16*)p;   p += (size_t)MPAD * CDIM * 2;

  // 1. casts (single launch)
  {
    const int total = MROWS * CDIM / 4 + QKVN * CDIM / 4 + CDIM * CDIM / 4;
    casts_kernel<<<(total + 255) / 256, 256, 0, stream>>>(x, xb, qkv_w, wqb, proj_w, wpb);
  }
  // 2. qkv = x @ qkv_w^T + qkv_b  (bf16 out). nMt=197, nNt=12, XCD-banded grid.
  gemm_bt<1><<<8 * 25 * 12, 256, 0, stream>>>(xb, wqb, qkv_b, qkvb,
                                              MPAD, QKVN, CDIM, 197, 12);
  // 3. kv partials + exp-sums
  kv_kernel<<<dim3(256, KVSPLIT), 256, 0, stream>>>(qkvb, kvpart, kvsum);
  kv_reduce_kernel<<<256, 256, 0, stream>>>(kvpart, kvsum, kvT);
  // 4. depthwise convs + EV fuse
  conv_all_kernel<<<dim3(BATCH, HEADS, 7), 256, 0, stream>>>(
      qkvb, w3, b3, w5, b5, w7, b7, evbuf);
  // 5. factor_att + CRPE -> attn (bf16)
  combine_kernel<<<dim3(256, 4), 256, 0, stream>>>(qkvb, kvT, evbuf, attn);
  // 6. out = attn @ proj_w^T + proj_b  (f32 out). nMt=197, nNt=4.
  gemm_bt<0><<<8 * 25 * 4, 256, 0, stream>>>(attn, wpb, proj_b, out,
                                             MROWS, CDIM, CDIM, 197, 4);
}

// Round 5
// 329.814 us; speedup vs baseline: 4.5535x; 1.0042x over previous
//
#include <hip/hip_runtime.h>
#include <cstdint>
#include <cstddef>

// CoaT factorized attention block, MI355X/gfx950.
// R5: GEMM retiled 128x128 -> 256x128 (512 thr, 8 waves, BK=64, XOR-8 swizzle,
// XCD banding kept). 25% fewer staged bytes/MFMA, half the blocks, 3 blk/CU
// x 8 waves for latency hiding. M padded 25120 -> 25344 (99 x 256).

typedef unsigned short u16;

#define HEADS 8
#define CHD   64
#define CDIM  512
#define NTOK  785
#define BATCH 32
#define MROWS (BATCH * NTOK)   // 25120
#define MPAD  25344            // 99 * 256
#define QKVN  1536
#define IMGHW 784
#define KVSPLIT 7

typedef float  f32x4  __attribute__((ext_vector_type(4)));
typedef __bf16 bf16x8 __attribute__((ext_vector_type(8)));

__device__ __forceinline__ u16 f2bf(float f) {
  union { float f; uint32_t u; } x; x.f = f;
  uint32_t r = x.u + 0x7fffu + ((x.u >> 16) & 1u);  // RNE
  return (u16)(r >> 16);
}
__device__ __forceinline__ float bf2f(u16 u) {
  union { uint32_t u; float f; } x; x.u = ((uint32_t)u) << 16;
  return x.f;
}
// packed f32x2 -> bf16x2 (low = a, high = b)
__device__ __forceinline__ uint32_t pk2(float a, float b) {
#if __has_builtin(__builtin_amdgcn_cvt_pk_bf16_f32)
  auto v = __builtin_amdgcn_cvt_pk_bf16_f32(a, b);
  union { decltype(v) v2; uint32_t u; } cv; cv.v2 = v; return cv.u;
#else
  return (uint32_t)f2bf(a) | ((uint32_t)f2bf(b) << 16);
#endif
}

// ---------------- merged f32 -> bf16 casts (x, qkv_w, proj_w) --------------
__global__ __launch_bounds__(256)
void casts_kernel(const float* __restrict__ x, u16* __restrict__ xb,
                  const float* __restrict__ w1, u16* __restrict__ w1b,
                  const float* __restrict__ w2, u16* __restrict__ w2b) {
  const int N1 = MROWS * CDIM / 4, N2 = QKVN * CDIM / 4, N3 = CDIM * CDIM / 4;
  int i = blockIdx.x * 256 + threadIdx.x;
  const float* src; u16* dst;
  if (i < N1)           { src = x;  dst = xb;  }
  else if (i < N1 + N2) { i -= N1;  src = w1; dst = w1b; }
  else if (i < N1 + N2 + N3) { i -= N1 + N2; src = w2; dst = w2b; }
  else return;
  float4 v = reinterpret_cast<const float4*>(src)[i];
  uint2 o; o.x = pk2(v.x, v.y); o.y = pk2(v.z, v.w);
  reinterpret_cast<uint2*>(dst)[i] = o;
}

// ---------------- async global->LDS, 16B per lane --------------------------
__device__ __forceinline__ void gld_lds16(const u16* g, u16* l) {
  __builtin_amdgcn_global_load_lds((__attribute__((address_space(1))) void*)g,
                                   (__attribute__((address_space(3))) void*)l,
                                   16, 0, 0);
}

// ---------------- bf16 MFMA GEMM, C = A @ W^T + bias -----------------------
// 256x128 tile, 512 threads = 8 waves in 4(row)x2(col); per wave 4x4 of
// 16x16x32 MFMA. BK=64 with XOR-8 chunk swizzle (global-side permutation:
// logical chunk c of row r lands at physical chunk c^(r&7); fragment reads
// hit 8 distinct bank-groups -> free 2-way only).
// Grid: flat 1D, XCD-banded, N-fastest (xcd = flat&7) -> A-tile read ~once
// per XCD L2.
template <int OUTBF16>
__global__ __launch_bounds__(512)
void gemm_bt(const u16* __restrict__ A, const u16* __restrict__ W,
             const float* __restrict__ bias, void* __restrict__ Cout,
             int Mstore, int N, int K, int nMt, int nNt) {
  __shared__ __align__(16) u16 lsA[256 * 64];   // 32 KB
  __shared__ __align__(16) u16 lsB[128 * 64];   // 16 KB
  const int flat = blockIdx.x;
  const int xcd = flat & 7, idx = flat >> 3;
  const int nt = idx % nNt;
  const int mt = (idx / nNt) * 8 + xcd;
  if (mt >= nMt) return;
  const int tile_m = mt * 256, tile_n = nt * 128;

  const int tid  = threadIdx.x;
  const int wave = tid >> 6, lane = tid & 63;
  const int quad = lane >> 4, l16 = lane & 15;
  const int wm = (wave & 3) * 64, wn = (wave >> 2) * 64;

  // staging: thread covers row s*64 + (tid>>3); loads global chunk
  // ((tid&7) ^ (row&7)) -> lands at physical chunk (tid&7).
  const int srow0 = tid >> 3;                        // 0..63
  const int scol  = ((tid & 7) ^ (srow0 & 7)) * 8;
  const int ldst  = srow0 * 64 + (tid & 7) * 8;      // + s*4096 (elems)

  f32x4 acc[4][4] = {};

  for (int k0 = 0; k0 < K; k0 += 64) {
#pragma unroll
    for (int s = 0; s < 4; ++s)
      gld_lds16(A + (size_t)(tile_m + s * 64 + srow0) * K + k0 + scol,
                &lsA[s * 4096 + ldst]);
#pragma unroll
    for (int s = 0; s < 2; ++s)
      gld_lds16(W + (size_t)(tile_n + s * 64 + srow0) * K + k0 + scol,
                &lsB[s * 4096 + ldst]);
    __syncthreads();
#pragma unroll
    for (int kk = 0; kk < 2; ++kk) {
      const int pch = ((kk * 4 + quad) ^ (l16 & 7)) * 8;  // physical chunk
      bf16x8 af[4], bfr[4];
#pragma unroll
      for (int i = 0; i < 4; ++i) {
        af[i]  = *reinterpret_cast<const bf16x8*>(&lsA[(wm + i * 16 + l16) * 64 + pch]);
        bfr[i] = *reinterpret_cast<const bf16x8*>(&lsB[(wn + i * 16 + l16) * 64 + pch]);
      }
#pragma unroll
      for (int i = 0; i < 4; ++i)
#pragma unroll
        for (int j = 0; j < 4; ++j)
          acc[i][j] = __builtin_amdgcn_mfma_f32_16x16x32_bf16(af[i], bfr[j], acc[i][j], 0, 0, 0);
    }
    __syncthreads();
  }

  // C/D layout: col = lane&15, row = quad*4 + reg
#pragma unroll
  for (int i = 0; i < 4; ++i) {
    const int mbase = tile_m + wm + i * 16 + quad * 4;
#pragma unroll
    for (int j = 0; j < 4; ++j) {
      const int n  = tile_n + wn + j * 16 + l16;
      const float bv = bias[n];
      const float v0 = acc[i][j][0] + bv, v1 = acc[i][j][1] + bv;
      const float v2 = acc[i][j][2] + bv, v3 = acc[i][j][3] + bv;
      if (OUTBF16) {
        u16* cp = reinterpret_cast<u16*>(Cout) + (size_t)mbase * N + n;
        const uint32_t p01 = pk2(v0, v1), p23 = pk2(v2, v3);
        if (mbase + 0 < Mstore) cp[0]            = (u16)p01;
        if (mbase + 1 < Mstore) cp[(size_t)N]    = (u16)(p01 >> 16);
        if (mbase + 2 < Mstore) cp[(size_t)N*2]  = (u16)p23;
        if (mbase + 3 < Mstore) cp[(size_t)N*3]  = (u16)(p23 >> 16);
      } else {
        float* cp = reinterpret_cast<float*>(Cout) + (size_t)mbase * N + n;
        if (mbase + 0 < Mstore) cp[0]           = v0;
        if (mbase + 1 < Mstore) cp[(size_t)N]   = v1;
        if (mbase + 2 < Mstore) cp[(size_t)N*2] = v2;
        if (mbase + 3 < Mstore) cp[(size_t)N*3] = v3;
      }
    }
  }
}

// ---------------- kv partials + exp-sum partials ---------------------------
// kvpart[bh][split][c][d] = sum_{n in split} exp(k[n,c]) * v[n,d]
// kvsum [bh][split][c]    = sum_{n in split} exp(k[n,c])
// No max subtraction: k ~ N(0,1), |k| small -> exp safe in f32.
__global__ __launch_bounds__(256)
void kv_kernel(const u16* __restrict__ qkv, float* __restrict__ kvpart,
               float* __restrict__ kvsum) {
  const int bh = blockIdx.x, split = blockIdx.y;
  const int b = bh >> 3, h = bh & 7;
  const int n_start = split * 113;
  const int n_end = min(NTOK, n_start + 113);
  const int t = threadIdx.x;
  const int d = t & 63, cq = t >> 6;
  __shared__ float e_s[32 * 64];
  __shared__ float v_s[32 * 64];
  const u16* kbase = qkv + (size_t)(b * NTOK) * QKVN + CDIM + h * CHD;
  const u16* vbase = kbase + CDIM;
  float acc[16];
#pragma unroll
  for (int i = 0; i < 16; ++i) acc[i] = 0.f;
  float s_part = 0.f;   // sum of exp over this thread's staged elems (c = t&63)

  for (int n0 = n_start; n0 < n_end; n0 += 32) {
    const int nc = min(32, n_end - n0);
    __syncthreads();
    for (int i = t; i < nc * 64; i += 256) {
      const int nl = i >> 6, c = i & 63;
      const float e = __expf(bf2f(kbase[(size_t)(n0 + nl) * QKVN + c]));
      e_s[i] = e; s_part += e;
      v_s[i] = bf2f(vbase[(size_t)(n0 + nl) * QKVN + c]);
    }
    __syncthreads();
    for (int nl = 0; nl < nc; ++nl) {
      const float vv = v_s[nl * 64 + d];
#pragma unroll
      for (int i = 0; i < 16; ++i)
        acc[i] += e_s[nl * 64 + cq * 16 + i] * vv;
    }
  }
#pragma unroll
  for (int i = 0; i < 16; ++i) {
    const int c = cq * 16 + i;
    kvpart[(((size_t)bh * KVSPLIT + split) * 64 + c) * 64 + d] = acc[i];
  }
  __syncthreads();
  e_s[t] = s_part;
  __syncthreads();
  if (t < 64)
    kvsum[((size_t)bh * KVSPLIT + split) * 64 + t] =
        e_s[t] + e_s[64 + t] + e_s[128 + t] + e_s[192 + t];
}

// ---------------- reduce partials -> kvT[bh][d][c] bf16 (B-operand layout) -
__global__ __launch_bounds__(256)
void kv_reduce_kernel(const float* __restrict__ kvpart, const float* __restrict__ kvsum,
                      u16* __restrict__ kvT) {
  const int bh = blockIdx.x;
  const int t = threadIdx.x;
  const int d = t & 63, cq = t >> 6;
#pragma unroll
  for (int cc = 0; cc < 16; ++cc) {
    const int c = cq * 16 + cc;
    float s = 0.f, S = 0.f;
#pragma unroll
    for (int sp = 0; sp < KVSPLIT; ++sp) {
      s += kvpart[(((size_t)bh * KVSPLIT + sp) * 64 + c) * 64 + d];
      S += kvsum[((size_t)bh * KVSPLIT + sp) * 64 + c];
    }
    kvT[(size_t)bh * 4096 + d * 64 + c] = f2bf(s / S);
  }
}

// ---------------- depthwise conv + EV fuse ---------------------------------
template <int KS>
__device__ __forceinline__ void conv_head(
    const u16* __restrict__ qkv, const float* __restrict__ wgt,
    const float* __restrict__ bias, int b, int head, int hh, int yt,
    u16* __restrict__ evbuf, u16* __restrict__ ls) {
  constexpr int PAD = KS / 2;
  constexpr int RIN = 4 + 2 * PAD;
  const int t = threadIdx.x;
  const int y0 = yt * 4;
  const u16* vimg = qkv + (size_t)(b * NTOK + 1) * QKVN + 2 * CDIM + head * 64;
  const int c8 = (t & 7) * 8;
  for (int pi = t >> 3; pi < RIN * 28; pi += 32) {
    const int ry = pi / 28, rx = pi - ry * 28;
    const int yy = y0 - PAD + ry;
    uint4 val = {0, 0, 0, 0};
    if (yy >= 0 && yy < 28)
      val = *reinterpret_cast<const uint4*>(vimg + (size_t)(yy * 28 + rx) * QKVN + c8);
    *reinterpret_cast<uint4*>(ls + pi * 64 + c8) = val;
  }
  __syncthreads();
  const int d = t & 63, yl = t >> 6;
  float wr[KS * KS];
  const float* wp = wgt + (hh * 64 + d) * KS * KS;
#pragma unroll
  for (int i = 0; i < KS * KS; ++i) wr[i] = wp[i];
  const float bv = bias[hh * 64 + d];
  float acc[28];
#pragma unroll
  for (int x = 0; x < 28; ++x) acc[x] = bv;
#pragma unroll
  for (int xx = 0; xx < 28; ++xx) {
    float col[KS];
#pragma unroll
    for (int r = 0; r < KS; ++r)
      col[r] = bf2f(ls[((yl + r) * 28 + xx) * 64 + d]);
#pragma unroll
    for (int j = 0; j < KS; ++j) {
      const int x = xx + PAD - j;
      if (x >= 0 && x < 28) {
#pragma unroll
        for (int r = 0; r < KS; ++r)
          acc[x] += col[r] * wr[r * KS + j];
      }
    }
  }
  const int p0 = (y0 + yl) * 28;
  const u16* qrow = qkv + (size_t)(b * NTOK + 1 + p0) * QKVN + head * 64 + d;
  u16* obase = evbuf + (((size_t)(b * 8 + head)) * IMGHW + p0) * 64 + d;
#pragma unroll
  for (int x = 0; x < 28; ++x) {
    const float ev = acc[x] * bf2f(qrow[(size_t)x * QKVN]);
    obase[(size_t)x * 64] = f2bf(ev);
  }
}

__global__ __launch_bounds__(256)
void conv_all_kernel(const u16* __restrict__ qkv,
                     const float* __restrict__ w3, const float* __restrict__ b3,
                     const float* __restrict__ w5, const float* __restrict__ b5,
                     const float* __restrict__ w7, const float* __restrict__ b7,
                     u16* __restrict__ evbuf) {
  __shared__ __align__(16) u16 ls[10 * 28 * 64];
  const int b = blockIdx.x, h = blockIdx.y, yt = blockIdx.z;
  if (h < 2)      conv_head<3>(qkv, w3, b3, b, h, h,     yt, evbuf, ls);
  else if (h < 5) conv_head<5>(qkv, w5, b5, b, h, h - 2, yt, evbuf, ls);
  else            conv_head<7>(qkv, w7, b7, b, h, h - 5, yt, evbuf, ls);
}

// ---------------- combine: factor_att via MFMA + CRPE ----------------------
__global__ __launch_bounds__(256)
void combine_kernel(const u16* __restrict__ qkv, const u16* __restrict__ kvT,
                    const u16* __restrict__ evbuf, u16* __restrict__ attn) {
  const int bh = blockIdx.x;
  const int b = bh >> 3, h = bh & 7;
  const int wave = threadIdx.x >> 6, lane = threadIdx.x & 63;
  const int quad = lane >> 4, l16 = lane & 15;
  const int tokbase = blockIdx.y * 256 + wave * 64;

  const u16* kvb = kvT + (size_t)bh * 4096;
  bf16x8 bfr[4][2];
#pragma unroll
  for (int j = 0; j < 4; ++j)
#pragma unroll
    for (int kk = 0; kk < 2; ++kk)
      bfr[j][kk] = *reinterpret_cast<const bf16x8*>(
          &kvb[(j * 16 + l16) * 64 + kk * 32 + quad * 8]);

  bf16x8 af[4][2];
#pragma unroll
  for (int i = 0; i < 4; ++i) {
    const int tok = min(tokbase + i * 16 + l16, NTOK - 1);
    const u16* qrow = qkv + (size_t)(b * NTOK + tok) * QKVN + h * CHD;
    af[i][0] = *reinterpret_cast<const bf16x8*>(&qrow[quad * 8]);
    af[i][1] = *reinterpret_cast<const bf16x8*>(&qrow[32 + quad * 8]);
  }

  f32x4 acc[4][4] = {};
#pragma unroll
  for (int kk = 0; kk < 2; ++kk)
#pragma unroll
    for (int i = 0; i < 4; ++i)
#pragma unroll
      for (int j = 0; j < 4; ++j)
        acc[i][j] = __builtin_amdgcn_mfma_f32_16x16x32_bf16(af[i][kk], bfr[j][kk], acc[i][j], 0, 0, 0);

  const float scale = 0.125f;
  const u16* evb = evbuf + (size_t)bh * IMGHW * 64;
#pragma unroll
  for (int i = 0; i < 4; ++i) {
#pragma unroll
    for (int r = 0; r < 4; ++r) {
      const int tok = tokbase + i * 16 + quad * 4 + r;
      if (tok < NTOK) {
#pragma unroll
        for (int j = 0; j < 4; ++j) {
          const int d = j * 16 + l16;
          float out = scale * acc[i][j][r];
          if (tok > 0) out += bf2f(evb[(size_t)(tok - 1) * 64 + d]);
          attn[(size_t)(b * NTOK + tok) * CDIM + h * CHD + d] = f2bf(out);
        }
      }
    }
  }
}

// ---------------- launch ---------------------------------------------------
extern "C" void kernel_launch(void* const* d_in, const int* in_sizes, int n_in,
                              void* d_out, int out_size, void* d_ws, size_t ws_size,
                              hipStream_t stream) {
  const float* x      = (const float*)d_in[0];
  const float* qkv_w  = (const float*)d_in[1];
  const float* qkv_b  = (const float*)d_in[2];
  const float* proj_w = (const float*)d_in[3];
  const float* proj_b = (const float*)d_in[4];
  const float* w3 = (const float*)d_in[5];
  const float* b3 = (const float*)d_in[6];
  const float* w5 = (const float*)d_in[7];
  const float* b5 = (const float*)d_in[8];
  const float* w7 = (const float*)d_in[9];
  const float* b7 = (const float*)d_in[10];
  float* out = (float*)d_out;

  char* p = (char*)d_ws;
  u16* xb    = (u16*)p;   p += (size_t)MPAD * CDIM * 2;
  u16* wqb   = (u16*)p;   p += (size_t)QKVN * CDIM * 2;
  u16* wpb   = (u16*)p;   p += (size_t)CDIM * CDIM * 2;
  u16* qkvb  = (u16*)p;   p += (size_t)MPAD * QKVN * 2;
  float* kvsum = (float*)p; p += (size_t)256 * KVSPLIT * 64 * 4;
  u16* kvT   = (u16*)p;   p += (size_t)256 * 64 * 64 * 2;
  // kvpart (f32, 29.4 MB) and evbuf (bf16, 25.7 MB) share one region:
  // kvpart dead after kv_reduce; conv writes evbuf afterwards.
  char* shared_region = p;
  float* kvpart = (float*)shared_region;
  u16*   evbuf  = (u16*)shared_region;
  p += (size_t)256 * KVSPLIT * 64 * 64 * 4;
  u16* attn  = (u16*)p;   p += (size_t)MPAD * CDIM * 2;

  // 1. casts (single launch)
  {
    const int total = MROWS * CDIM / 4 + QKVN * CDIM / 4 + CDIM * CDIM / 4;
    casts_kernel<<<(total + 255) / 256, 256, 0, stream>>>(x, xb, qkv_w, wqb, proj_w, wpb);
  }
  // 2. qkv = x @ qkv_w^T + qkv_b  (bf16 out). nMt=99, nNt=12, XCD-banded grid.
  gemm_bt<1><<<13 * 8 * 12, 512, 0, stream>>>(xb, wqb, qkv_b, qkvb,
                                              MPAD, QKVN, CDIM, 99, 12);
  // 3. kv partials + exp-sums
  kv_kernel<<<dim3(256, KVSPLIT), 256, 0, stream>>>(qkvb, kvpart, kvsum);
  kv_reduce_kernel<<<256, 256, 0, stream>>>(kvpart, kvsum, kvT);
  // 4. depthwise convs + EV fuse
  conv_all_kernel<<<dim3(BATCH, HEADS, 7), 256, 0, stream>>>(
      qkvb, w3, b3, w5, b5, w7, b7, evbuf);
  // 5. factor_att + CRPE -> attn (bf16)
  combine_kernel<<<dim3(256, 4), 256, 0, stream>>>(qkvb, kvT, evbuf, attn);
  // 6. out = attn @ proj_w^T + proj_b  (f32 out). nMt=99, nNt=4.
  gemm_bt<0><<<13 * 8 * 4, 512, 0, stream>>>(attn, wpb, proj_b, out,
                                             MROWS, CDIM, CDIM, 99, 4);
}